// Round 15
// baseline (285.386 us; speedup 1.0000x reference)
//
#include <hip/hip_runtime.h>

// PQN soft-quantization: x[32768,1024] f32, c[1024,256] f32 -> out[32768,1024] f32
// D=1024, M=8 subspaces of L=128, K=256 codes, logits scaled by 2*ALPHA=20.
//
// R15 = R12's kernel (52 VGPR, no spill, 159 us) re-hosted on 1024-thread
// blocks to double resident waves: 2 blocks/CU x 16 waves = 32 waves/CU
// (HW thread max), vs R12's measured 13.7. Residency math: LDS 2x64KB=128KB
// <=160 ✓; VGPR must be <=64 -> amdgpu_waves_per_eu(8) lowers the allocator
// cap to 512/8=64 (R5 showed the attr is a MIN-occupancy constraint: it can
// lower the cap, never raise usage; R12 demand measured 52 < 64).
// Grid 512 = exactly one resident generation (no 2nd-gen ramp, unlike R14).
// R14's zero-LDS variant regressed (267 us): phase-2 A-frags from L2 added
// 16 serial L2 latencies per wave-iter; csB in LDS is load-bearing. Reverted.
//
// Per wave-iter (16 samples), per chunk a (64 codes):
//   phase 1: acc[4] += ws[rho rows 64a..][l] . x^T      (A from global/L2)
//   online softmax: chunk max -> rescale acc2/sp by exp(m_old-m_new)
//   phase 2: acc2[8] += csB[:, 64a..] . p_chunk         (A from LDS)
// sched_barrier(0) fences pin in-flight frag regs (the R12 discovery: full
// unrolling, not live-set, caused every earlier spill).
// rho row-permutation makes packed exp words feed phase-2 B verbatim.

#define D_  1024
#define K_  256
#define L_  128

typedef _Float16 f16;
typedef f16 f16x8 __attribute__((ext_vector_type(8)));
typedef f16 f16x4 __attribute__((ext_vector_type(4)));
typedef float f32x4 __attribute__((ext_vector_type(4)));
typedef unsigned int u32;

// prep: c[(m*128+l)*256 + code] f32 -> ws[m][rho(code)][l] f16 (512 KB)
__global__ __launch_bounds__(128)
void pqn_prep(const float* __restrict__ c, f16* __restrict__ ws) {
    const int b   = blockIdx.x;          // m*256 + code
    const int m   = b >> 8;
    const int cc  = b & 255;
    const int l   = threadIdx.x;         // 0..127
    const int rho = (cc & ~31) | ((cc & 4) << 2) | ((cc & 24) >> 1) | (cc & 3);
    float v = c[(size_t)(m * L_ + l) * K_ + cc];
    ws[((size_t)m * K_ + rho) * L_ + l] = (f16)v;   // 256-B rows, coalesced
}

__global__ __launch_bounds__(1024) __attribute__((amdgpu_waves_per_eu(8)))
void pqn_main(const float* __restrict__ x, const float* __restrict__ c,
              const f16* __restrict__ ws, float* __restrict__ out) {
    __shared__ unsigned char csB[65536];  // [128 l][256 codes] f16, 512-B rows, ^=(l&7)<<4

    const int tid  = threadIdx.x;
    const int m    = blockIdx.x >> 6;    // 8 subspaces x 64 blocks
    const int bm   = blockIdx.x & 63;
    const int lane = tid & 63;
    const int w    = tid >> 6;           // wave 0..15
    const int n    = lane & 15;          // sample column
    const int g    = lane >> 4;          // quarter-wave (k-group)

    // ---- stage csB (64 KB) with all 1024 threads ----
    const float* cm = c + (size_t)m * L_ * K_;       // cm[l*256 + k]
    {
        const int R0 = tid >> 6;         // 0..15
        const int f  = tid & 63;         // code quad
        #pragma unroll
        for (int b = 0; b < 4; ++b) {
            int R  = b * 16 + R0;        // 0..63
            int l0 = 2 * R;
            float4 a  = *reinterpret_cast<const float4*>(cm + (size_t)l0 * K_ + 4 * f);
            float4 bb = *reinterpret_cast<const float4*>(cm + (size_t)(l0 + 1) * K_ + 4 * f);
            f16x4 va = {(f16)a.x, (f16)a.y, (f16)a.z, (f16)a.w};
            f16x4 vb = {(f16)bb.x, (f16)bb.y, (f16)bb.z, (f16)bb.w};
            *reinterpret_cast<f16x4*>(csB + l0 * 512       + ((8 * f) ^ ((l0 & 7) << 4))) = va;
            *reinterpret_cast<f16x4*>(csB + (l0 + 1) * 512 + ((8 * f) ^ (((l0 + 1) & 7) << 4))) = vb;
        }
    }
    __syncthreads();

    const f16* wsm = ws + (size_t)m * (K_ * L_) + (size_t)n * L_ + 8 * g;

    #pragma unroll 1
    for (int it = 0; it < 2; ++it) {
        const int row0 = bm * 512 + it * 256 + w * 16 + n;

        // ---- x load + cvt to f16 fragments + row norm ----
        const float* px = x + (size_t)row0 * D_ + m * L_ + 8 * g;
        float ss = 0.f;
        f16x8 bf[4];
        #pragma unroll
        for (int ks = 0; ks < 4; ++ks) {
            float4 lo = *reinterpret_cast<const float4*>(px + 32 * ks);
            float4 hi = *reinterpret_cast<const float4*>(px + 32 * ks + 4);
            ss = fmaf(lo.x, lo.x, ss); ss = fmaf(lo.y, lo.y, ss);
            ss = fmaf(lo.z, lo.z, ss); ss = fmaf(lo.w, lo.w, ss);
            ss = fmaf(hi.x, hi.x, ss); ss = fmaf(hi.y, hi.y, ss);
            ss = fmaf(hi.z, hi.z, ss); ss = fmaf(hi.w, hi.w, ss);
            bf[ks][0] = (f16)lo.x; bf[ks][1] = (f16)lo.y;
            bf[ks][2] = (f16)lo.z; bf[ks][3] = (f16)lo.w;
            bf[ks][4] = (f16)hi.x; bf[ks][5] = (f16)hi.y;
            bf[ks][6] = (f16)hi.z; bf[ks][7] = (f16)hi.w;
        }
        ss += __shfl_xor(ss, 16);
        ss += __shfl_xor(ss, 32);
        const float fac = 20.0f / fmaxf(sqrtf(ss), 1e-12f);

        // ---- online-softmax fused phase1 -> phase2, 4 chunks of 64 codes ----
        f32x4 acc2[8];
        const f32x4 fzero = {0.f, 0.f, 0.f, 0.f};
        #pragma unroll
        for (int lt = 0; lt < 8; ++lt) acc2[lt] = fzero;
        float mrun = -3.0e38f;
        float sp   = 0.f;

        #pragma unroll 1
        for (int a = 0; a < 4; ++a) {
            // phase-1 chunk: z over codes [64a, 64a+64)
            f32x4 acc[4];
            #pragma unroll
            for (int ct = 0; ct < 4; ++ct) acc[ct] = fzero;
            #pragma unroll
            for (int ks = 0; ks < 4; ++ks) {
                #pragma unroll
                for (int ct = 0; ct < 4; ++ct) {
                    f16x8 af = *reinterpret_cast<const f16x8*>(
                        wsm + (a * 64 + ct * 16) * L_ + 32 * ks);
                    acc[ct] = __builtin_amdgcn_mfma_f32_16x16x32_f16(af, bf[ks], acc[ct], 0, 0, 0);
                }
                __builtin_amdgcn_sched_barrier(0);   // cap in-flight ws frags at 16 regs
            }
            // logits + chunk max (column-wide)
            float cmax = -3.0e38f;
            #pragma unroll
            for (int ct = 0; ct < 4; ++ct) {
                acc[ct][0] *= fac; acc[ct][1] *= fac;
                acc[ct][2] *= fac; acc[ct][3] *= fac;
                cmax = fmaxf(cmax, fmaxf(fmaxf(acc[ct][0], acc[ct][1]),
                                         fmaxf(acc[ct][2], acc[ct][3])));
            }
            cmax = fmaxf(cmax, __shfl_xor(cmax, 16));
            cmax = fmaxf(cmax, __shfl_xor(cmax, 32));
            const float mnew = fmaxf(mrun, cmax);
            const float r = __expf(mrun - mnew);
            mrun = mnew;
            sp *= r;
            #pragma unroll
            for (int lt = 0; lt < 8; ++lt) {
                acc2[lt][0] *= r; acc2[lt][1] *= r;
                acc2[lt][2] *= r; acc2[lt][3] *= r;
            }
            // exp + per-lane sum + pack
            u32 P[8];
            #pragma unroll
            for (int ct = 0; ct < 4; ++ct) {
                float p0 = __expf(acc[ct][0] - mrun);
                float p1 = __expf(acc[ct][1] - mrun);
                float p2 = __expf(acc[ct][2] - mrun);
                float p3 = __expf(acc[ct][3] - mrun);
                sp += (p0 + p1) + (p2 + p3);
                P[2 * ct]     = __builtin_bit_cast(u32, __builtin_amdgcn_cvt_pkrtz(p0, p1));
                P[2 * ct + 1] = __builtin_bit_cast(u32, __builtin_amdgcn_cvt_pkrtz(p2, p3));
            }
            __builtin_amdgcn_sched_barrier(0);
            // phase-2 chunk: acc2 += csB[:, chunk] . p_chunk
            #pragma unroll
            for (int j = 0; j < 2; ++j) {
                union { f16x8 v; u32 q[4]; } pb;
                pb.q[0] = P[4 * j + 0]; pb.q[1] = P[4 * j + 1];
                pb.q[2] = P[4 * j + 2]; pb.q[3] = P[4 * j + 3];
                const int ks2 = 2 * a + j;
                #pragma unroll
                for (int lt = 0; lt < 8; ++lt) {
                    f16x8 a2 = *reinterpret_cast<const f16x8*>(
                        csB + (lt * 16 + n) * 512 + ((64 * ks2 + 16 * g) ^ ((n & 7) << 4)));
                    acc2[lt] = __builtin_amdgcn_mfma_f32_16x16x32_f16(a2, pb.v, acc2[lt], 0, 0, 0);
                }
                __builtin_amdgcn_sched_barrier(0);   // cap in-flight csB frags at 32 regs
            }
        }

        // ---- final sum reduce + normalized store ----
        sp += __shfl_xor(sp, 16);
        sp += __shfl_xor(sp, 32);
        const float invS = 1.0f / sp;

        float* po = out + (size_t)row0 * D_ + m * L_ + 4 * g;
        #pragma unroll
        for (int lt = 0; lt < 8; ++lt) {
            f32x4 v;
            v[0] = acc2[lt][0] * invS; v[1] = acc2[lt][1] * invS;
            v[2] = acc2[lt][2] * invS; v[3] = acc2[lt][3] * invS;
            *reinterpret_cast<f32x4*>(po + 16 * lt) = v;
        }
    }
}

extern "C" void kernel_launch(void* const* d_in, const int* in_sizes, int n_in,
                              void* d_out, int out_size, void* d_ws, size_t ws_size,
                              hipStream_t stream) {
    const float* x = (const float*)d_in[0];   // [32768, 1024] f32
    const float* c = (const float*)d_in[1];   // [1024, 256]   f32
    float* out = (float*)d_out;               // [32768, 1024] f32
    f16* ws = (f16*)d_ws;                     // 512 KB: [8][256 rho][128] f16
    (void)in_sizes; (void)n_in; (void)out_size; (void)ws_size;

    pqn_prep<<<dim3(2048), dim3(128), 0, stream>>>(c, ws);
    pqn_main<<<dim3(512), dim3(1024), 0, stream>>>(x, c, ws, out);
}

// Round 16
// 164.450 us; speedup vs baseline: 1.7354x; 1.7354x over previous
//
#include <hip/hip_runtime.h>

// PQN soft-quantization: x[32768,1024] f32, c[1024,256] f32 -> out[32768,1024] f32
// D=1024, M=8 subspaces of L=128, K=256 codes, logits scaled by 2*ALPHA=20.
//
// R16 = R15 WITHOUT amdgpu_waves_per_eu. The round-15 experiment proved the
// attribute sets the VGPR cap too aggressively (min-8-waves -> 32-reg cap ->
// spill: FETCH 357/WRITE 426 MB at 80% occupancy = 285 us), while R12 proved
// plain compilation with sched_barrier fences keeps demand at 52 regs with
// zero spill. At usage <= 64 the HW grants 8 waves/EU (pool 512/EU); LDS
// 2 x 64 KB <= 160 KB -> 2 resident 16-wave blocks = 32 waves/CU, no-spill.
// Grid 512 x 1024 thr = exactly one resident generation, 2 row-iters/wave.
//
// Kernel body = validated R12 structure (156 us at 13.7 waves/CU):
// per wave-iter (16 samples), per chunk a (64 codes):
//   phase 1: acc[4] += ws[rho rows 64a..][l] . x^T      (A from global/L2)
//   online softmax: chunk max -> rescale acc2/sp by exp(m_old-m_new)
//   phase 2: acc2[8] += csB[:, 64a..] . p_chunk         (A from LDS, swizzled)
// sched_barrier(0) fences pin in-flight frag regs (R12 discovery: full
// unrolling -- not the live set -- caused every earlier spill).
// rho row-permutation makes packed exp words feed phase-2 B verbatim.

#define D_  1024
#define K_  256
#define L_  128

typedef _Float16 f16;
typedef f16 f16x8 __attribute__((ext_vector_type(8)));
typedef f16 f16x4 __attribute__((ext_vector_type(4)));
typedef float f32x4 __attribute__((ext_vector_type(4)));
typedef unsigned int u32;

// prep: c[(m*128+l)*256 + code] f32 -> ws[m][rho(code)][l] f16 (512 KB)
__global__ __launch_bounds__(128)
void pqn_prep(const float* __restrict__ c, f16* __restrict__ ws) {
    const int b   = blockIdx.x;          // m*256 + code
    const int m   = b >> 8;
    const int cc  = b & 255;
    const int l   = threadIdx.x;         // 0..127
    const int rho = (cc & ~31) | ((cc & 4) << 2) | ((cc & 24) >> 1) | (cc & 3);
    float v = c[(size_t)(m * L_ + l) * K_ + cc];
    ws[((size_t)m * K_ + rho) * L_ + l] = (f16)v;   // 256-B rows, coalesced
}

__global__ __launch_bounds__(1024)
void pqn_main(const float* __restrict__ x, const float* __restrict__ c,
              const f16* __restrict__ ws, float* __restrict__ out) {
    __shared__ unsigned char csB[65536];  // [128 l][256 codes] f16, 512-B rows, ^=(l&7)<<4

    const int tid  = threadIdx.x;
    const int m    = blockIdx.x >> 6;    // 8 subspaces x 64 blocks
    const int bm   = blockIdx.x & 63;
    const int lane = tid & 63;
    const int w    = tid >> 6;           // wave 0..15
    const int n    = lane & 15;          // sample column
    const int g    = lane >> 4;          // quarter-wave (k-group)

    // ---- stage csB (64 KB) with all 1024 threads ----
    const float* cm = c + (size_t)m * L_ * K_;       // cm[l*256 + k]
    {
        const int R0 = tid >> 6;         // 0..15
        const int f  = tid & 63;         // code quad
        #pragma unroll
        for (int b = 0; b < 4; ++b) {
            int R  = b * 16 + R0;        // 0..63
            int l0 = 2 * R;
            float4 a  = *reinterpret_cast<const float4*>(cm + (size_t)l0 * K_ + 4 * f);
            float4 bb = *reinterpret_cast<const float4*>(cm + (size_t)(l0 + 1) * K_ + 4 * f);
            f16x4 va = {(f16)a.x, (f16)a.y, (f16)a.z, (f16)a.w};
            f16x4 vb = {(f16)bb.x, (f16)bb.y, (f16)bb.z, (f16)bb.w};
            *reinterpret_cast<f16x4*>(csB + l0 * 512       + ((8 * f) ^ ((l0 & 7) << 4))) = va;
            *reinterpret_cast<f16x4*>(csB + (l0 + 1) * 512 + ((8 * f) ^ (((l0 + 1) & 7) << 4))) = vb;
        }
    }
    __syncthreads();

    const f16* wsm = ws + (size_t)m * (K_ * L_) + (size_t)n * L_ + 8 * g;

    #pragma unroll 1
    for (int it = 0; it < 2; ++it) {
        const int row0 = bm * 512 + it * 256 + w * 16 + n;

        // ---- x load + cvt to f16 fragments + row norm ----
        const float* px = x + (size_t)row0 * D_ + m * L_ + 8 * g;
        float ss = 0.f;
        f16x8 bf[4];
        #pragma unroll
        for (int ks = 0; ks < 4; ++ks) {
            float4 lo = *reinterpret_cast<const float4*>(px + 32 * ks);
            float4 hi = *reinterpret_cast<const float4*>(px + 32 * ks + 4);
            ss = fmaf(lo.x, lo.x, ss); ss = fmaf(lo.y, lo.y, ss);
            ss = fmaf(lo.z, lo.z, ss); ss = fmaf(lo.w, lo.w, ss);
            ss = fmaf(hi.x, hi.x, ss); ss = fmaf(hi.y, hi.y, ss);
            ss = fmaf(hi.z, hi.z, ss); ss = fmaf(hi.w, hi.w, ss);
            bf[ks][0] = (f16)lo.x; bf[ks][1] = (f16)lo.y;
            bf[ks][2] = (f16)lo.z; bf[ks][3] = (f16)lo.w;
            bf[ks][4] = (f16)hi.x; bf[ks][5] = (f16)hi.y;
            bf[ks][6] = (f16)hi.z; bf[ks][7] = (f16)hi.w;
        }
        ss += __shfl_xor(ss, 16);
        ss += __shfl_xor(ss, 32);
        const float fac = 20.0f / fmaxf(sqrtf(ss), 1e-12f);

        // ---- online-softmax fused phase1 -> phase2, 4 chunks of 64 codes ----
        f32x4 acc2[8];
        const f32x4 fzero = {0.f, 0.f, 0.f, 0.f};
        #pragma unroll
        for (int lt = 0; lt < 8; ++lt) acc2[lt] = fzero;
        float mrun = -3.0e38f;
        float sp   = 0.f;

        #pragma unroll 1
        for (int a = 0; a < 4; ++a) {
            // phase-1 chunk: z over codes [64a, 64a+64)
            f32x4 acc[4];
            #pragma unroll
            for (int ct = 0; ct < 4; ++ct) acc[ct] = fzero;
            #pragma unroll
            for (int ks = 0; ks < 4; ++ks) {
                #pragma unroll
                for (int ct = 0; ct < 4; ++ct) {
                    f16x8 af = *reinterpret_cast<const f16x8*>(
                        wsm + (a * 64 + ct * 16) * L_ + 32 * ks);
                    acc[ct] = __builtin_amdgcn_mfma_f32_16x16x32_f16(af, bf[ks], acc[ct], 0, 0, 0);
                }
                __builtin_amdgcn_sched_barrier(0);   // cap in-flight ws frags at 16 regs
            }
            // logits + chunk max (column-wide)
            float cmax = -3.0e38f;
            #pragma unroll
            for (int ct = 0; ct < 4; ++ct) {
                acc[ct][0] *= fac; acc[ct][1] *= fac;
                acc[ct][2] *= fac; acc[ct][3] *= fac;
                cmax = fmaxf(cmax, fmaxf(fmaxf(acc[ct][0], acc[ct][1]),
                                         fmaxf(acc[ct][2], acc[ct][3])));
            }
            cmax = fmaxf(cmax, __shfl_xor(cmax, 16));
            cmax = fmaxf(cmax, __shfl_xor(cmax, 32));
            const float mnew = fmaxf(mrun, cmax);
            const float r = __expf(mrun - mnew);
            mrun = mnew;
            sp *= r;
            #pragma unroll
            for (int lt = 0; lt < 8; ++lt) {
                acc2[lt][0] *= r; acc2[lt][1] *= r;
                acc2[lt][2] *= r; acc2[lt][3] *= r;
            }
            // exp + per-lane sum + pack
            u32 P[8];
            #pragma unroll
            for (int ct = 0; ct < 4; ++ct) {
                float p0 = __expf(acc[ct][0] - mrun);
                float p1 = __expf(acc[ct][1] - mrun);
                float p2 = __expf(acc[ct][2] - mrun);
                float p3 = __expf(acc[ct][3] - mrun);
                sp += (p0 + p1) + (p2 + p3);
                P[2 * ct]     = __builtin_bit_cast(u32, __builtin_amdgcn_cvt_pkrtz(p0, p1));
                P[2 * ct + 1] = __builtin_bit_cast(u32, __builtin_amdgcn_cvt_pkrtz(p2, p3));
            }
            __builtin_amdgcn_sched_barrier(0);
            // phase-2 chunk: acc2 += csB[:, chunk] . p_chunk
            #pragma unroll
            for (int j = 0; j < 2; ++j) {
                union { f16x8 v; u32 q[4]; } pb;
                pb.q[0] = P[4 * j + 0]; pb.q[1] = P[4 * j + 1];
                pb.q[2] = P[4 * j + 2]; pb.q[3] = P[4 * j + 3];
                const int ks2 = 2 * a + j;
                #pragma unroll
                for (int lt = 0; lt < 8; ++lt) {
                    f16x8 a2 = *reinterpret_cast<const f16x8*>(
                        csB + (lt * 16 + n) * 512 + ((64 * ks2 + 16 * g) ^ ((n & 7) << 4)));
                    acc2[lt] = __builtin_amdgcn_mfma_f32_16x16x32_f16(a2, pb.v, acc2[lt], 0, 0, 0);
                }
                __builtin_amdgcn_sched_barrier(0);   // cap in-flight csB frags at 32 regs
            }
        }

        // ---- final sum reduce + normalized store ----
        sp += __shfl_xor(sp, 16);
        sp += __shfl_xor(sp, 32);
        const float invS = 1.0f / sp;

        float* po = out + (size_t)row0 * D_ + m * L_ + 4 * g;
        #pragma unroll
        for (int lt = 0; lt < 8; ++lt) {
            f32x4 v;
            v[0] = acc2[lt][0] * invS; v[1] = acc2[lt][1] * invS;
            v[2] = acc2[lt][2] * invS; v[3] = acc2[lt][3] * invS;
            *reinterpret_cast<f32x4*>(po + 16 * lt) = v;
        }
    }
}

extern "C" void kernel_launch(void* const* d_in, const int* in_sizes, int n_in,
                              void* d_out, int out_size, void* d_ws, size_t ws_size,
                              hipStream_t stream) {
    const float* x = (const float*)d_in[0];   // [32768, 1024] f32
    const float* c = (const float*)d_in[1];   // [1024, 256]   f32
    float* out = (float*)d_out;               // [32768, 1024] f32
    f16* ws = (f16*)d_ws;                     // 512 KB: [8][256 rho][128] f16
    (void)in_sizes; (void)n_in; (void)out_size; (void)ws_size;

    pqn_prep<<<dim3(2048), dim3(128), 0, stream>>>(c, ws);
    pqn_main<<<dim3(512), dim3(1024), 0, stream>>>(x, c, ws, out);
}

// Round 17
// 158.047 us; speedup vs baseline: 1.8057x; 1.0405x over previous
//
#include <hip/hip_runtime.h>

// PQN soft-quantization: x[32768,1024] f32, c[1024,256] f32 -> out[32768,1024] f32
// D=1024, M=8 subspaces of L=128, K=256 codes, logits scaled by 2*ALPHA=20.
//
// R17 = R12 host config (grid 512 x 512thr, csA in d_ws via L2, csB in 64KB
// LDS, sched_barrier discipline) + CHUNK-LEVEL LOAD PIPELINE:
//   per chunk a: [16 MFMAs consume frag buffer F] -> [re-issue all 16 loads
//   of chunk a+1 into F] -> [softmax(a) + phase2(a) (~1500cy) covers them].
// Rationale (R12/13/16 data): total regs = arch(52) + acc(~64) => only 4
// waves/SIMD ever resident; fences capped MLP at 4 loads in flight with a
// vmcnt(0) drain per ks-group => ~95% stall on queue-inflated L2/L3 latency
// (in+out+ws ~ 270MB slightly overflows the 256MB L3; x is part-HBM).
// This trades 1 wave of TLP (F = +64 arch regs -> 3 waves/SIMD) for 4x MLP
// with real cover. a=3 wraps to chunk 0 (frags are it-invariant).
// rho row-permutation makes packed exp words feed phase-2 B verbatim.

#define D_  1024
#define K_  256
#define L_  128

typedef _Float16 f16;
typedef f16 f16x8 __attribute__((ext_vector_type(8)));
typedef f16 f16x4 __attribute__((ext_vector_type(4)));
typedef float f32x4 __attribute__((ext_vector_type(4)));
typedef unsigned int u32;

// prep: c[(m*128+l)*256 + code] f32 -> ws[m][rho(code)][l] f16 (512 KB)
__global__ __launch_bounds__(128)
void pqn_prep(const float* __restrict__ c, f16* __restrict__ ws) {
    const int b   = blockIdx.x;          // m*256 + code
    const int m   = b >> 8;
    const int cc  = b & 255;
    const int l   = threadIdx.x;         // 0..127
    const int rho = (cc & ~31) | ((cc & 4) << 2) | ((cc & 24) >> 1) | (cc & 3);
    float v = c[(size_t)(m * L_ + l) * K_ + cc];
    ws[((size_t)m * K_ + rho) * L_ + l] = (f16)v;   // 256-B rows, coalesced
}

__global__ __launch_bounds__(512)
void pqn_main(const float* __restrict__ x, const float* __restrict__ c,
              const f16* __restrict__ ws, float* __restrict__ out) {
    __shared__ unsigned char csB[65536];  // [128 l][256 codes] f16, 512-B rows, ^=(l&7)<<4

    const int tid  = threadIdx.x;
    const int m    = blockIdx.x >> 6;    // 8 subspaces x 64 blocks
    const int bm   = blockIdx.x & 63;
    const int lane = tid & 63;
    const int w    = tid >> 6;           // wave 0..7
    const int n    = lane & 15;          // sample column
    const int g    = lane >> 4;          // quarter-wave (k-group)

    // ---- stage csB (64 KB) with all 512 threads ----
    const float* cm = c + (size_t)m * L_ * K_;       // cm[l*256 + k]
    {
        const int R0 = tid >> 6;         // 0..7
        const int f  = tid & 63;         // code quad
        #pragma unroll
        for (int b = 0; b < 8; ++b) {
            int R  = b * 8 + R0;         // 0..63
            int l0 = 2 * R;
            float4 a  = *reinterpret_cast<const float4*>(cm + (size_t)l0 * K_ + 4 * f);
            float4 bb = *reinterpret_cast<const float4*>(cm + (size_t)(l0 + 1) * K_ + 4 * f);
            f16x4 va = {(f16)a.x, (f16)a.y, (f16)a.z, (f16)a.w};
            f16x4 vb = {(f16)bb.x, (f16)bb.y, (f16)bb.z, (f16)bb.w};
            *reinterpret_cast<f16x4*>(csB + l0 * 512       + ((8 * f) ^ ((l0 & 7) << 4))) = va;
            *reinterpret_cast<f16x4*>(csB + (l0 + 1) * 512 + ((8 * f) ^ (((l0 + 1) & 7) << 4))) = vb;
        }
    }
    __syncthreads();

    const f16* wsm = ws + (size_t)m * (K_ * L_) + (size_t)n * L_ + 8 * g;

    // ---- prologue: fill frag buffer F with chunk 0 (it-invariant) ----
    f16x8 F[4][4];   // [ct][ks]
    #pragma unroll
    for (int ct = 0; ct < 4; ++ct)
        #pragma unroll
        for (int ks = 0; ks < 4; ++ks)
            F[ct][ks] = *reinterpret_cast<const f16x8*>(wsm + (ct * 16) * L_ + 32 * ks);

    #pragma unroll 1
    for (int it = 0; it < 4; ++it) {
        const int row0 = bm * 512 + it * 128 + w * 16 + n;

        // ---- x load + cvt to f16 fragments + row norm ----
        const float* px = x + (size_t)row0 * D_ + m * L_ + 8 * g;
        float ss = 0.f;
        f16x8 bf[4];
        #pragma unroll
        for (int ks = 0; ks < 4; ++ks) {
            float4 lo = *reinterpret_cast<const float4*>(px + 32 * ks);
            float4 hi = *reinterpret_cast<const float4*>(px + 32 * ks + 4);
            ss = fmaf(lo.x, lo.x, ss); ss = fmaf(lo.y, lo.y, ss);
            ss = fmaf(lo.z, lo.z, ss); ss = fmaf(lo.w, lo.w, ss);
            ss = fmaf(hi.x, hi.x, ss); ss = fmaf(hi.y, hi.y, ss);
            ss = fmaf(hi.z, hi.z, ss); ss = fmaf(hi.w, hi.w, ss);
            bf[ks][0] = (f16)lo.x; bf[ks][1] = (f16)lo.y;
            bf[ks][2] = (f16)lo.z; bf[ks][3] = (f16)lo.w;
            bf[ks][4] = (f16)hi.x; bf[ks][5] = (f16)hi.y;
            bf[ks][6] = (f16)hi.z; bf[ks][7] = (f16)hi.w;
        }
        ss += __shfl_xor(ss, 16);
        ss += __shfl_xor(ss, 32);
        const float fac = 20.0f / fmaxf(sqrtf(ss), 1e-12f);

        // ---- online-softmax fused phase1 -> phase2, 4 chunks of 64 codes ----
        f32x4 acc2[8];
        const f32x4 fzero = {0.f, 0.f, 0.f, 0.f};
        #pragma unroll
        for (int lt = 0; lt < 8; ++lt) acc2[lt] = fzero;
        float mrun = -3.0e38f;
        float sp   = 0.f;

        #pragma unroll 1
        for (int a = 0; a < 4; ++a) {
            // ---- phase-1: 16 MFMAs consume F (waits on F's loads) ----
            f32x4 acc[4];
            #pragma unroll
            for (int ct = 0; ct < 4; ++ct) acc[ct] = fzero;
            #pragma unroll
            for (int ks = 0; ks < 4; ++ks)
                #pragma unroll
                for (int ct = 0; ct < 4; ++ct)
                    acc[ct] = __builtin_amdgcn_mfma_f32_16x16x32_f16(F[ct][ks], bf[ks], acc[ct], 0, 0, 0);
            __builtin_amdgcn_sched_barrier(0);

            // ---- re-issue F with NEXT chunk's 16 frags (fly under softmax+p2) ----
            {
                const f16* wsn = wsm + (((a + 1) & 3) * 64) * L_;
                #pragma unroll
                for (int ct = 0; ct < 4; ++ct)
                    #pragma unroll
                    for (int ks = 0; ks < 4; ++ks)
                        F[ct][ks] = *reinterpret_cast<const f16x8*>(wsn + (ct * 16) * L_ + 32 * ks);
            }
            __builtin_amdgcn_sched_barrier(0);

            // ---- softmax chunk (VALU cover for the 16 in-flight loads) ----
            float cmax = -3.0e38f;
            #pragma unroll
            for (int ct = 0; ct < 4; ++ct) {
                acc[ct][0] *= fac; acc[ct][1] *= fac;
                acc[ct][2] *= fac; acc[ct][3] *= fac;
                cmax = fmaxf(cmax, fmaxf(fmaxf(acc[ct][0], acc[ct][1]),
                                         fmaxf(acc[ct][2], acc[ct][3])));
            }
            cmax = fmaxf(cmax, __shfl_xor(cmax, 16));
            cmax = fmaxf(cmax, __shfl_xor(cmax, 32));
            const float mnew = fmaxf(mrun, cmax);
            const float r = __expf(mrun - mnew);
            mrun = mnew;
            sp *= r;
            #pragma unroll
            for (int lt = 0; lt < 8; ++lt) {
                acc2[lt][0] *= r; acc2[lt][1] *= r;
                acc2[lt][2] *= r; acc2[lt][3] *= r;
            }
            u32 P[8];
            #pragma unroll
            for (int ct = 0; ct < 4; ++ct) {
                float p0 = __expf(acc[ct][0] - mrun);
                float p1 = __expf(acc[ct][1] - mrun);
                float p2 = __expf(acc[ct][2] - mrun);
                float p3 = __expf(acc[ct][3] - mrun);
                sp += (p0 + p1) + (p2 + p3);
                P[2 * ct]     = __builtin_bit_cast(u32, __builtin_amdgcn_cvt_pkrtz(p0, p1));
                P[2 * ct + 1] = __builtin_bit_cast(u32, __builtin_amdgcn_cvt_pkrtz(p2, p3));
            }
            __builtin_amdgcn_sched_barrier(0);

            // ---- phase-2 chunk: acc2 += csB[:, chunk] . p_chunk (LDS) ----
            #pragma unroll
            for (int j = 0; j < 2; ++j) {
                union { f16x8 v; u32 q[4]; } pb;
                pb.q[0] = P[4 * j + 0]; pb.q[1] = P[4 * j + 1];
                pb.q[2] = P[4 * j + 2]; pb.q[3] = P[4 * j + 3];
                const int ks2 = 2 * a + j;
                #pragma unroll
                for (int lt = 0; lt < 8; ++lt) {
                    f16x8 a2 = *reinterpret_cast<const f16x8*>(
                        csB + (lt * 16 + n) * 512 + ((64 * ks2 + 16 * g) ^ ((n & 7) << 4)));
                    acc2[lt] = __builtin_amdgcn_mfma_f32_16x16x32_f16(a2, pb.v, acc2[lt], 0, 0, 0);
                }
                __builtin_amdgcn_sched_barrier(0);
            }
        }

        // ---- final sum reduce + normalized store ----
        sp += __shfl_xor(sp, 16);
        sp += __shfl_xor(sp, 32);
        const float invS = 1.0f / sp;

        float* po = out + (size_t)row0 * D_ + m * L_ + 4 * g;
        #pragma unroll
        for (int lt = 0; lt < 8; ++lt) {
            f32x4 v;
            v[0] = acc2[lt][0] * invS; v[1] = acc2[lt][1] * invS;
            v[2] = acc2[lt][2] * invS; v[3] = acc2[lt][3] * invS;
            *reinterpret_cast<f32x4*>(po + 16 * lt) = v;
        }
    }
}

extern "C" void kernel_launch(void* const* d_in, const int* in_sizes, int n_in,
                              void* d_out, int out_size, void* d_ws, size_t ws_size,
                              hipStream_t stream) {
    const float* x = (const float*)d_in[0];   // [32768, 1024] f32
    const float* c = (const float*)d_in[1];   // [1024, 256]   f32
    float* out = (float*)d_out;               // [32768, 1024] f32
    f16* ws = (f16*)d_ws;                     // 512 KB: [8][256 rho][128] f16
    (void)in_sizes; (void)n_in; (void)out_size; (void)ws_size;

    pqn_prep<<<dim3(2048), dim3(128), 0, stream>>>(c, ws);
    pqn_main<<<dim3(512), dim3(512), 0, stream>>>(x, c, ws, out);
}

// Round 18
// 124.753 us; speedup vs baseline: 2.2876x; 1.2669x over previous
//
#include <hip/hip_runtime.h>

// PQN soft-quantization: x[32768,1024] f32, c[1024,256] f32 -> out[32768,1024] f32
// D=1024, M=8 subspaces of L=128, K=256 codes, logits scaled by 2*ALPHA=20.
//
// R18: line-request-reuse redesign. R12-R17 all sit at ~157us regardless of
// TLP (7-16 waves/CU) and MLP (4-16): the kernel is bound by L1/TA 64B-line
// request throughput (~82k lines/CU @ ~4.6cy/line; model also fits R14=267
// and R15=285). Fix: each wave-iter processes 32 samples as TWO 16-sample
// tiles that SHARE every ws fragment (F) and every phase-2 LDS fragment (a2)
// -> ws lines per sample halve (1024 lines now serve 32 samples), LDS reads
// halve, addressing VALU halves. Lines/CU: 82k -> ~49k => ~100us predicted.
// Needs ~210 VGPRs -> 256-thr blocks + __launch_bounds__(256,1) (proven 256
// cap in R1/R7/R8), 2 blocks/CU (2x64KB LDS), 8 waves/CU (R17: 7 suffice).
// Chunk-pipelined F reload + sched_barrier(0) fences (R12 discovery) keep
// the allocator honest; #pragma unroll 1 on chunk/iter loops.
//
// Per 32-sample wave-iter, per chunk a (64 codes):
//   phase 1: acc0/acc1 += F . bf0 / F . bf1     (F = ws rho-rows via L2)
//   F <- chunk a+1 (16 loads fly under softmax+phase2)
//   online softmax per tile (chunk max -> rescale acc2/sp)
//   phase 2: a2 = csB LDS frag (tile-independent); acc2_0 += a2.pb0,
//            acc2_1 += a2.pb1  (one LDS read feeds two MFMAs)
// rho row-permutation makes packed exp words feed phase-2 B verbatim.

#define D_  1024
#define K_  256
#define L_  128

typedef _Float16 f16;
typedef f16 f16x8 __attribute__((ext_vector_type(8)));
typedef f16 f16x4 __attribute__((ext_vector_type(4)));
typedef float f32x4 __attribute__((ext_vector_type(4)));
typedef unsigned int u32;

// prep: c[(m*128+l)*256 + code] f32 -> ws[m][rho(code)][l] f16 (512 KB)
__global__ __launch_bounds__(128)
void pqn_prep(const float* __restrict__ c, f16* __restrict__ ws) {
    const int b   = blockIdx.x;          // m*256 + code
    const int m   = b >> 8;
    const int cc  = b & 255;
    const int l   = threadIdx.x;         // 0..127
    const int rho = (cc & ~31) | ((cc & 4) << 2) | ((cc & 24) >> 1) | (cc & 3);
    float v = c[(size_t)(m * L_ + l) * K_ + cc];
    ws[((size_t)m * K_ + rho) * L_ + l] = (f16)v;   // 256-B rows, coalesced
}

__global__ __launch_bounds__(256, 1)
void pqn_main(const float* __restrict__ x, const float* __restrict__ c,
              const f16* __restrict__ ws, float* __restrict__ out) {
    __shared__ unsigned char csB[65536];  // [128 l][256 codes] f16, 512-B rows, ^=(l&7)<<4

    const int tid  = threadIdx.x;
    const int m    = blockIdx.x >> 6;    // 8 subspaces x 64 blocks
    const int bm   = blockIdx.x & 63;
    const int lane = tid & 63;
    const int w    = tid >> 6;           // wave 0..3
    const int n    = lane & 15;          // sample column within tile
    const int g    = lane >> 4;          // quarter-wave (k-group)

    // ---- stage csB (64 KB) with all 256 threads ----
    const float* cm = c + (size_t)m * L_ * K_;       // cm[l*256 + k]
    {
        const int R0 = tid >> 6;         // 0..3
        const int f  = tid & 63;         // code quad
        #pragma unroll
        for (int b = 0; b < 16; ++b) {
            int R  = b * 4 + R0;         // 0..63
            int l0 = 2 * R;
            float4 a  = *reinterpret_cast<const float4*>(cm + (size_t)l0 * K_ + 4 * f);
            float4 bb = *reinterpret_cast<const float4*>(cm + (size_t)(l0 + 1) * K_ + 4 * f);
            f16x4 va = {(f16)a.x, (f16)a.y, (f16)a.z, (f16)a.w};
            f16x4 vb = {(f16)bb.x, (f16)bb.y, (f16)bb.z, (f16)bb.w};
            *reinterpret_cast<f16x4*>(csB + l0 * 512       + ((8 * f) ^ ((l0 & 7) << 4))) = va;
            *reinterpret_cast<f16x4*>(csB + (l0 + 1) * 512 + ((8 * f) ^ (((l0 + 1) & 7) << 4))) = vb;
        }
    }
    __syncthreads();

    const f16* wsm = ws + (size_t)m * (K_ * L_) + (size_t)n * L_ + 8 * g;

    // ---- prologue: fill frag buffer F with chunk 0 (iteration-invariant) ----
    f16x8 F[4][4];   // [ct][ks]
    #pragma unroll
    for (int ct = 0; ct < 4; ++ct)
        #pragma unroll
        for (int ks = 0; ks < 4; ++ks)
            F[ct][ks] = *reinterpret_cast<const f16x8*>(wsm + (ct * 16) * L_ + 32 * ks);

    #pragma unroll 1
    for (int it = 0; it < 4; ++it) {
        const int rbase = bm * 512 + it * 128 + w * 32 + n;   // tile0 row; tile1 = +16

        // ---- x load + cvt to f16 fragments + row norms (both tiles) ----
        float fac0, fac1;
        f16x8 bf0[4], bf1[4];
        #pragma unroll
        for (int t = 0; t < 2; ++t) {
            const float* px = x + (size_t)(rbase + t * 16) * D_ + m * L_ + 8 * g;
            float ss = 0.f;
            f16x8* bft = t ? bf1 : bf0;
            #pragma unroll
            for (int ks = 0; ks < 4; ++ks) {
                float4 lo = *reinterpret_cast<const float4*>(px + 32 * ks);
                float4 hi = *reinterpret_cast<const float4*>(px + 32 * ks + 4);
                ss = fmaf(lo.x, lo.x, ss); ss = fmaf(lo.y, lo.y, ss);
                ss = fmaf(lo.z, lo.z, ss); ss = fmaf(lo.w, lo.w, ss);
                ss = fmaf(hi.x, hi.x, ss); ss = fmaf(hi.y, hi.y, ss);
                ss = fmaf(hi.z, hi.z, ss); ss = fmaf(hi.w, hi.w, ss);
                bft[ks][0] = (f16)lo.x; bft[ks][1] = (f16)lo.y;
                bft[ks][2] = (f16)lo.z; bft[ks][3] = (f16)lo.w;
                bft[ks][4] = (f16)hi.x; bft[ks][5] = (f16)hi.y;
                bft[ks][6] = (f16)hi.z; bft[ks][7] = (f16)hi.w;
            }
            ss += __shfl_xor(ss, 16);
            ss += __shfl_xor(ss, 32);
            float fc = 20.0f / fmaxf(sqrtf(ss), 1e-12f);
            if (t) fac1 = fc; else fac0 = fc;
        }

        f32x4 acc2a[8], acc2b[8];
        const f32x4 fzero = {0.f, 0.f, 0.f, 0.f};
        #pragma unroll
        for (int lt = 0; lt < 8; ++lt) { acc2a[lt] = fzero; acc2b[lt] = fzero; }
        float mr0 = -3.0e38f, sp0 = 0.f;
        float mr1 = -3.0e38f, sp1 = 0.f;

        #pragma unroll 1
        for (int a = 0; a < 4; ++a) {
            // ---- phase 1: both tiles consume F ----
            f32x4 acc0[4], acc1[4];
            #pragma unroll
            for (int ct = 0; ct < 4; ++ct) { acc0[ct] = fzero; acc1[ct] = fzero; }
            #pragma unroll
            for (int ks = 0; ks < 4; ++ks)
                #pragma unroll
                for (int ct = 0; ct < 4; ++ct) {
                    acc0[ct] = __builtin_amdgcn_mfma_f32_16x16x32_f16(F[ct][ks], bf0[ks], acc0[ct], 0, 0, 0);
                    acc1[ct] = __builtin_amdgcn_mfma_f32_16x16x32_f16(F[ct][ks], bf1[ks], acc1[ct], 0, 0, 0);
                }
            __builtin_amdgcn_sched_barrier(0);

            // ---- re-issue F with next chunk's frags (fly under softmax+p2) ----
            {
                const f16* wsn = wsm + (((a + 1) & 3) * 64) * L_;
                #pragma unroll
                for (int ct = 0; ct < 4; ++ct)
                    #pragma unroll
                    for (int ks = 0; ks < 4; ++ks)
                        F[ct][ks] = *reinterpret_cast<const f16x8*>(wsn + (ct * 16) * L_ + 32 * ks);
            }
            __builtin_amdgcn_sched_barrier(0);

            // ---- softmax per tile ----
            u32 P0[8], P1[8];
            #pragma unroll
            for (int t = 0; t < 2; ++t) {
                f32x4* acc = t ? acc1 : acc0;
                f32x4* a2  = t ? acc2b : acc2a;
                float fac  = t ? fac1 : fac0;
                float mrun = t ? mr1 : mr0;
                float sp   = t ? sp1 : sp0;
                u32* P     = t ? P1 : P0;

                float cmax = -3.0e38f;
                #pragma unroll
                for (int ct = 0; ct < 4; ++ct) {
                    acc[ct][0] *= fac; acc[ct][1] *= fac;
                    acc[ct][2] *= fac; acc[ct][3] *= fac;
                    cmax = fmaxf(cmax, fmaxf(fmaxf(acc[ct][0], acc[ct][1]),
                                             fmaxf(acc[ct][2], acc[ct][3])));
                }
                cmax = fmaxf(cmax, __shfl_xor(cmax, 16));
                cmax = fmaxf(cmax, __shfl_xor(cmax, 32));
                const float mnew = fmaxf(mrun, cmax);
                const float r = __expf(mrun - mnew);
                mrun = mnew;
                sp *= r;
                #pragma unroll
                for (int lt = 0; lt < 8; ++lt) {
                    a2[lt][0] *= r; a2[lt][1] *= r;
                    a2[lt][2] *= r; a2[lt][3] *= r;
                }
                #pragma unroll
                for (int ct = 0; ct < 4; ++ct) {
                    float p0 = __expf(acc[ct][0] - mrun);
                    float p1 = __expf(acc[ct][1] - mrun);
                    float p2 = __expf(acc[ct][2] - mrun);
                    float p3 = __expf(acc[ct][3] - mrun);
                    sp += (p0 + p1) + (p2 + p3);
                    P[2 * ct]     = __builtin_bit_cast(u32, __builtin_amdgcn_cvt_pkrtz(p0, p1));
                    P[2 * ct + 1] = __builtin_bit_cast(u32, __builtin_amdgcn_cvt_pkrtz(p2, p3));
                }
                if (t) { mr1 = mrun; sp1 = sp; } else { mr0 = mrun; sp0 = sp; }
            }
            __builtin_amdgcn_sched_barrier(0);

            // ---- phase 2: one LDS fragment feeds BOTH tiles ----
            #pragma unroll
            for (int j = 0; j < 2; ++j) {
                union { f16x8 v; u32 q[4]; } pb0, pb1;
                pb0.q[0] = P0[4 * j + 0]; pb0.q[1] = P0[4 * j + 1];
                pb0.q[2] = P0[4 * j + 2]; pb0.q[3] = P0[4 * j + 3];
                pb1.q[0] = P1[4 * j + 0]; pb1.q[1] = P1[4 * j + 1];
                pb1.q[2] = P1[4 * j + 2]; pb1.q[3] = P1[4 * j + 3];
                const int ks2 = 2 * a + j;
                #pragma unroll
                for (int lt = 0; lt < 8; ++lt) {
                    f16x8 a2 = *reinterpret_cast<const f16x8*>(
                        csB + (lt * 16 + n) * 512 + ((64 * ks2 + 16 * g) ^ ((n & 7) << 4)));
                    acc2a[lt] = __builtin_amdgcn_mfma_f32_16x16x32_f16(a2, pb0.v, acc2a[lt], 0, 0, 0);
                    acc2b[lt] = __builtin_amdgcn_mfma_f32_16x16x32_f16(a2, pb1.v, acc2b[lt], 0, 0, 0);
                }
                __builtin_amdgcn_sched_barrier(0);
            }
        }

        // ---- final sum reduce + normalized stores (both tiles) ----
        sp0 += __shfl_xor(sp0, 16); sp0 += __shfl_xor(sp0, 32);
        sp1 += __shfl_xor(sp1, 16); sp1 += __shfl_xor(sp1, 32);
        const float iS0 = 1.0f / sp0;
        const float iS1 = 1.0f / sp1;

        float* po0 = out + (size_t)rbase * D_ + m * L_ + 4 * g;
        float* po1 = po0 + (size_t)16 * D_;
        #pragma unroll
        for (int lt = 0; lt < 8; ++lt) {
            f32x4 v0, v1;
            v0[0] = acc2a[lt][0] * iS0; v0[1] = acc2a[lt][1] * iS0;
            v0[2] = acc2a[lt][2] * iS0; v0[3] = acc2a[lt][3] * iS0;
            v1[0] = acc2b[lt][0] * iS1; v1[1] = acc2b[lt][1] * iS1;
            v1[2] = acc2b[lt][2] * iS1; v1[3] = acc2b[lt][3] * iS1;
            *reinterpret_cast<f32x4*>(po0 + 16 * lt) = v0;
            *reinterpret_cast<f32x4*>(po1 + 16 * lt) = v1;
        }
    }
}

extern "C" void kernel_launch(void* const* d_in, const int* in_sizes, int n_in,
                              void* d_out, int out_size, void* d_ws, size_t ws_size,
                              hipStream_t stream) {
    const float* x = (const float*)d_in[0];   // [32768, 1024] f32
    const float* c = (const float*)d_in[1];   // [1024, 256]   f32
    float* out = (float*)d_out;               // [32768, 1024] f32
    f16* ws = (f16*)d_ws;                     // 512 KB: [8][256 rho][128] f16
    (void)in_sizes; (void)n_in; (void)out_size; (void)ws_size;

    pqn_prep<<<dim3(2048), dim3(128), 0, stream>>>(c, ws);
    pqn_main<<<dim3(512), dim3(256), 0, stream>>>(x, c, ws, out);
}

// Round 19
// 83.226 us; speedup vs baseline: 3.4290x; 1.4990x over previous
//
#include <hip/hip_runtime.h>

// PQN soft-quantization: x[32768,1024] f32, c[1024,256] f32 -> out[32768,1024] f32
// D=1024, M=8 subspaces of L=128, K=256 codes, logits scaled by 2*ALPHA=20.
//
// R19: dual-LDS codebook, zero steady-state codebook line traffic.
// R18 established the kernel is L1/TA line-request bound and ws fragment
// loads are 67% of all lines (1024/1536 per 32-sample wave-iter). Fix: stage
// csA (rho-permuted, from ws) into LDS once per block alongside csB; LDS
// reads cost no TA lines. Steady lines = x+out only: ~20k/CU vs R18's 49k.
// R7-R9 ran dual-LDS at 325+us, but those rounds spilled under full-unroll
// register hoisting (the 490MB "mystery" FETCH); R12's sched_barrier
// discipline holds demand at 52-60 VGPR -> fits the 128 cap of 512-thr
// blocks with zero spill. 128KB LDS -> 1 block/CU x 8 waves.
//
// Per wave-iter (16 samples), per chunk a (64 codes):
//   phase 1: acc[4] += csA_lds[rho rows 64a..] . x^T   (ds_read_b128, swz)
//   online softmax: chunk max -> rescale acc2/sp
//   phase 2: acc2[8] += csB_lds[:, 64a..] . p_chunk
// rho row-permutation makes packed exp words feed phase-2 B verbatim
// (validated R8-R18). XOR swizzle ^(row&7)<<4 on both arrays: 16-lane row
// groups land 2-way max on banks (free, m136).

#define D_  1024
#define K_  256
#define L_  128

typedef _Float16 f16;
typedef f16 f16x8 __attribute__((ext_vector_type(8)));
typedef f16 f16x4 __attribute__((ext_vector_type(4)));
typedef float f32x4 __attribute__((ext_vector_type(4)));
typedef unsigned int u32;

// prep: c[(m*128+l)*256 + code] f32 -> ws[m][rho(code)][l] f16 (512 KB)
__global__ __launch_bounds__(128)
void pqn_prep(const float* __restrict__ c, f16* __restrict__ ws) {
    const int b   = blockIdx.x;          // m*256 + code
    const int m   = b >> 8;
    const int cc  = b & 255;
    const int l   = threadIdx.x;         // 0..127
    const int rho = (cc & ~31) | ((cc & 4) << 2) | ((cc & 24) >> 1) | (cc & 3);
    float v = c[(size_t)(m * L_ + l) * K_ + cc];
    ws[((size_t)m * K_ + rho) * L_ + l] = (f16)v;   // 256-B rows, coalesced
}

__global__ __launch_bounds__(512)
void pqn_main(const float* __restrict__ x, const float* __restrict__ c,
              const f16* __restrict__ ws, float* __restrict__ out) {
    __shared__ unsigned char lds[131072];
    unsigned char* csA = lds;            // [256 rho-rows][128 l] f16, 256-B rows, ^(r&7)<<4
    unsigned char* csB = lds + 65536;    // [128 l][256 codes] f16, 512-B rows, ^(l&7)<<4

    const int tid  = threadIdx.x;
    const int m    = blockIdx.x >> 6;    // 8 subspaces x 64 blocks
    const int bm   = blockIdx.x & 63;
    const int lane = tid & 63;
    const int w    = tid >> 6;           // wave 0..7
    const int n    = lane & 15;          // sample column
    const int g    = lane >> 4;          // quarter-wave (k-group)

    // ---- stage csA from ws: swizzled 64-KB copy (coalesced 16-B granules) ----
    {
        const f16* wsm0 = ws + (size_t)m * (K_ * L_);
        #pragma unroll
        for (int i = 0; i < 8; ++i) {
            int idx = i * 512 + tid;     // 0..4095 granules of 16 B
            int r   = idx >> 4;          // rho row 0..255
            int q   = idx & 15;          // 16-B granule within row
            f16x8 v = *reinterpret_cast<const f16x8*>(wsm0 + (size_t)idx * 8);
            *reinterpret_cast<f16x8*>(csA + r * 256 + ((q * 16) ^ ((r & 7) << 4))) = v;
        }
    }
    // ---- stage csB from c (f32 -> f16, swizzled; R12 pattern) ----
    const float* cm = c + (size_t)m * L_ * K_;       // cm[l*256 + k]
    {
        const int R0 = tid >> 6;         // 0..7
        const int f  = tid & 63;         // code quad
        #pragma unroll
        for (int b = 0; b < 8; ++b) {
            int R  = b * 8 + R0;         // 0..63
            int l0 = 2 * R;
            float4 a  = *reinterpret_cast<const float4*>(cm + (size_t)l0 * K_ + 4 * f);
            float4 bb = *reinterpret_cast<const float4*>(cm + (size_t)(l0 + 1) * K_ + 4 * f);
            f16x4 va = {(f16)a.x, (f16)a.y, (f16)a.z, (f16)a.w};
            f16x4 vb = {(f16)bb.x, (f16)bb.y, (f16)bb.z, (f16)bb.w};
            *reinterpret_cast<f16x4*>(csB + l0 * 512       + ((8 * f) ^ ((l0 & 7) << 4))) = va;
            *reinterpret_cast<f16x4*>(csB + (l0 + 1) * 512 + ((8 * f) ^ (((l0 + 1) & 7) << 4))) = vb;
        }
    }
    __syncthreads();

    #pragma unroll 1
    for (int it = 0; it < 4; ++it) {
        const int row0 = bm * 512 + it * 128 + w * 16 + n;

        // ---- x load + cvt to f16 fragments + row norm ----
        const float* px = x + (size_t)row0 * D_ + m * L_ + 8 * g;
        float ss = 0.f;
        f16x8 bf[4];
        #pragma unroll
        for (int ks = 0; ks < 4; ++ks) {
            float4 lo = *reinterpret_cast<const float4*>(px + 32 * ks);
            float4 hi = *reinterpret_cast<const float4*>(px + 32 * ks + 4);
            ss = fmaf(lo.x, lo.x, ss); ss = fmaf(lo.y, lo.y, ss);
            ss = fmaf(lo.z, lo.z, ss); ss = fmaf(lo.w, lo.w, ss);
            ss = fmaf(hi.x, hi.x, ss); ss = fmaf(hi.y, hi.y, ss);
            ss = fmaf(hi.z, hi.z, ss); ss = fmaf(hi.w, hi.w, ss);
            bf[ks][0] = (f16)lo.x; bf[ks][1] = (f16)lo.y;
            bf[ks][2] = (f16)lo.z; bf[ks][3] = (f16)lo.w;
            bf[ks][4] = (f16)hi.x; bf[ks][5] = (f16)hi.y;
            bf[ks][6] = (f16)hi.z; bf[ks][7] = (f16)hi.w;
        }
        ss += __shfl_xor(ss, 16);
        ss += __shfl_xor(ss, 32);
        const float fac = 20.0f / fmaxf(sqrtf(ss), 1e-12f);

        // ---- online-softmax fused phase1 -> phase2, 4 chunks of 64 codes ----
        f32x4 acc2[8];
        const f32x4 fzero = {0.f, 0.f, 0.f, 0.f};
        #pragma unroll
        for (int lt = 0; lt < 8; ++lt) acc2[lt] = fzero;
        float mrun = -3.0e38f;
        float sp   = 0.f;

        #pragma unroll 1
        for (int a = 0; a < 4; ++a) {
            // phase-1 chunk: z over codes [64a, 64a+64), A-frags from LDS csA
            f32x4 acc[4];
            #pragma unroll
            for (int ct = 0; ct < 4; ++ct) acc[ct] = fzero;
            #pragma unroll
            for (int ks = 0; ks < 4; ++ks) {
                #pragma unroll
                for (int ct = 0; ct < 4; ++ct) {
                    f16x8 af = *reinterpret_cast<const f16x8*>(
                        csA + (a * 64 + ct * 16 + n) * 256 +
                        ((64 * ks + 16 * g) ^ ((n & 7) << 4)));
                    acc[ct] = __builtin_amdgcn_mfma_f32_16x16x32_f16(af, bf[ks], acc[ct], 0, 0, 0);
                }
                __builtin_amdgcn_sched_barrier(0);   // reg discipline (R12)
            }
            // logits + chunk max (column-wide)
            float cmax = -3.0e38f;
            #pragma unroll
            for (int ct = 0; ct < 4; ++ct) {
                acc[ct][0] *= fac; acc[ct][1] *= fac;
                acc[ct][2] *= fac; acc[ct][3] *= fac;
                cmax = fmaxf(cmax, fmaxf(fmaxf(acc[ct][0], acc[ct][1]),
                                         fmaxf(acc[ct][2], acc[ct][3])));
            }
            cmax = fmaxf(cmax, __shfl_xor(cmax, 16));
            cmax = fmaxf(cmax, __shfl_xor(cmax, 32));
            const float mnew = fmaxf(mrun, cmax);
            const float r = __expf(mrun - mnew);
            mrun = mnew;
            sp *= r;
            #pragma unroll
            for (int lt = 0; lt < 8; ++lt) {
                acc2[lt][0] *= r; acc2[lt][1] *= r;
                acc2[lt][2] *= r; acc2[lt][3] *= r;
            }
            // exp + per-lane sum + pack
            u32 P[8];
            #pragma unroll
            for (int ct = 0; ct < 4; ++ct) {
                float p0 = __expf(acc[ct][0] - mrun);
                float p1 = __expf(acc[ct][1] - mrun);
                float p2 = __expf(acc[ct][2] - mrun);
                float p3 = __expf(acc[ct][3] - mrun);
                sp += (p0 + p1) + (p2 + p3);
                P[2 * ct]     = __builtin_bit_cast(u32, __builtin_amdgcn_cvt_pkrtz(p0, p1));
                P[2 * ct + 1] = __builtin_bit_cast(u32, __builtin_amdgcn_cvt_pkrtz(p2, p3));
            }
            __builtin_amdgcn_sched_barrier(0);
            // phase-2 chunk: acc2 += csB[:, chunk] . p_chunk
            #pragma unroll
            for (int j = 0; j < 2; ++j) {
                union { f16x8 v; u32 q[4]; } pb;
                pb.q[0] = P[4 * j + 0]; pb.q[1] = P[4 * j + 1];
                pb.q[2] = P[4 * j + 2]; pb.q[3] = P[4 * j + 3];
                const int ks2 = 2 * a + j;
                #pragma unroll
                for (int lt = 0; lt < 8; ++lt) {
                    f16x8 a2 = *reinterpret_cast<const f16x8*>(
                        csB + (lt * 16 + n) * 512 + ((64 * ks2 + 16 * g) ^ ((n & 7) << 4)));
                    acc2[lt] = __builtin_amdgcn_mfma_f32_16x16x32_f16(a2, pb.v, acc2[lt], 0, 0, 0);
                }
                __builtin_amdgcn_sched_barrier(0);
            }
        }

        // ---- final sum reduce + normalized store ----
        sp += __shfl_xor(sp, 16);
        sp += __shfl_xor(sp, 32);
        const float invS = 1.0f / sp;

        float* po = out + (size_t)row0 * D_ + m * L_ + 4 * g;
        #pragma unroll
        for (int lt = 0; lt < 8; ++lt) {
            f32x4 v;
            v[0] = acc2[lt][0] * invS; v[1] = acc2[lt][1] * invS;
            v[2] = acc2[lt][2] * invS; v[3] = acc2[lt][3] * invS;
            *reinterpret_cast<f32x4*>(po + 16 * lt) = v;
        }
    }
}

extern "C" void kernel_launch(void* const* d_in, const int* in_sizes, int n_in,
                              void* d_out, int out_size, void* d_ws, size_t ws_size,
                              hipStream_t stream) {
    const float* x = (const float*)d_in[0];   // [32768, 1024] f32
    const float* c = (const float*)d_in[1];   // [1024, 256]   f32
    float* out = (float*)d_out;               // [32768, 1024] f32
    f16* ws = (f16*)d_ws;                     // 512 KB: [8][256 rho][128] f16
    (void)in_sizes; (void)n_in; (void)out_size; (void)ws_size;

    pqn_prep<<<dim3(2048), dim3(128), 0, stream>>>(c, ws);
    pqn_main<<<dim3(512), dim3(512), 0, stream>>>(x, c, ws, out);
}